// Round 2
// baseline (327.798 us; speedup 1.0000x reference)
//
#include <hip/hip_runtime.h>

#define NGRAPH 4096
#define NNODE  64
#define NDIM   128
#define NLAYER 3
#define PH 136   // sh pitch (ushorts): 68 dwords === 4 mod 32 -> proven b128 row-read pattern
#define PZ 72    // zbuf pitch (ushorts): 36 dwords === 4 mod 32 (same family as R8's PA=72)

typedef __attribute__((ext_vector_type(8))) short short8;
typedef __attribute__((ext_vector_type(4))) float f32x4;
typedef __bf16 bf16x2 __attribute__((ext_vector_type(2)));

static __device__ inline ushort f2bf(float f) {  // RNE fp32 -> bf16 (fallback path)
  unsigned u = __float_as_uint(f);
  u += 0x7FFF + ((u >> 16) & 1);
  return (ushort)(u >> 16);
}

// packed fp32x2 -> bf16x2 in one HW instr on gfx950 (v_cvt_pk_bf16_f32)
static __device__ inline unsigned pkbf(float x, float y) {
#if __has_builtin(__builtin_amdgcn_cvt_pk_bf16_f32)
  bf16x2 v = __builtin_amdgcn_cvt_pk_bf16_f32(x, y);
  return __builtin_bit_cast(unsigned, v);
#else
  return (unsigned)f2bf(x) | ((unsigned)f2bf(y) << 16);
#endif
}

// W in bf16, native [l][k_out][d] layout (B-frag reads W rows directly).
__device__ __align__(16) ushort g_wbf[NLAYER * NDIM * NDIM];

__global__ __launch_bounds__(256) void convert_w(const float* __restrict__ W) {
  int i = blockIdx.x * 256 + threadIdx.x;   // 192 blocks, exact
  g_wbf[i] = f2bf(W[i]);
}

// R10 "split-z" restructure (post-mortem of R9: LDS diet worked, but 4-wave
// blocks + per-wave redundant global adj loads regressed).  Keep R8's 8-wave
// blocks + cooperative coalesced staging; restructure the math:
//  - m1 partitioned as 1 node-tile x 4 kout-slabs per wave -> each h row read
//    by only 2 waves (32 ah b128/block-layer vs R8's 128).
//  - z written to LDS TRANSPOSED (zT[kout][node]) as packed C-frags ->
//    m2's A-frag is one contiguous ds_read_b128; all 128 bpermutes deleted.
//  - (I+A) B-frags layer-invariant -> hoisted to 32 VGPRs once per block from
//    the LDS-staged copy; the staging buffer is then recycled as zT (35 KB LDS).
//  - 2 barriers/layer (zT exchange, h exchange), h overwritten in place.
__global__ __launch_bounds__(512, 8) void mpnn_mfma(
    const int* __restrict__ fps, const float* __restrict__ adj,
    const float* __restrict__ emb, const float* __restrict__ bias,
    float* __restrict__ out) {
  __shared__ __align__(16) ushort sh[NNODE * PH];    // h (in-place)      17408 B
  __shared__ __align__(16) ushort zbuf[NDIM * PZ];   // adj stage -> zT   18432 B

  const int g    = blockIdx.x;
  const int t    = threadIdx.x;
  const int w    = t >> 6;        // wave 0..7
  const int lane = t & 63;
  const int r    = lane & 15;     // MFMA row/col index
  const int q    = lane >> 4;     // quad 0..3
  const int mt    = w & 3;          // m1: this wave's 16-node tile
  const int kbase = (w >> 2) * 64;  // m1: this wave's 64-wide kout region (4 slabs)
  const int n0    = w << 4;         // m2: this wave's 16-wide d slab

  // ---- gather h0 = bf16(emb[fps]) into sh ----
  const int* fg = fps + g * NNODE;
#pragma unroll
  for (int it = 0; it < 4; ++it) {
    int idx = it * 512 + t;               // 2048 float4s
    int n = idx >> 5;
    int c = (idx & 31) << 2;
    float4 v = *(const float4*)(emb + fg[n] * NDIM + c);
    uint2 u = {pkbf(v.x, v.y), pkbf(v.z, v.w)};
    *(uint2*)(sh + n * PH + c) = u;
  }

  // ---- adjacency -> LDS: bf16(I + A), staged once, cooperatively coalesced ----
  const float* adjg = adj + (size_t)g * NNODE * NNODE;
#pragma unroll
  for (int it = 0; it < 2; ++it) {
    int idx = it * 512 + t;               // 1024 float4s
    int n = idx >> 4;
    int c = (idx & 15) << 2;
    float4 v = *(const float4*)(adjg + n * NNODE + c);
    v.x += (n == c + 0) ? 1.0f : 0.0f;    // fold residual: I + A
    v.y += (n == c + 1) ? 1.0f : 0.0f;
    v.z += (n == c + 2) ? 1.0f : 0.0f;
    v.w += (n == c + 3) ? 1.0f : 0.0f;
    uint2 u = {pkbf(v.x, v.y), pkbf(v.z, v.w)};
    *(uint2*)(zbuf + n * PZ + c) = u;
  }
  __syncthreads();

  // ---- (I+A) B-frags -> registers, once per block (layer-invariant) ----
  // fbr[kh][nt] lane(r,q): (I+A)[node'=nt*16+r][node=kh*32+8q+e]
  short8 fbr[2][4];
#pragma unroll
  for (int kh = 0; kh < 2; ++kh)
#pragma unroll
    for (int nt = 0; nt < 4; ++nt)
      fbr[kh][nt] = *(const short8*)(zbuf + (nt * 16 + r) * PZ + kh * 32 + 8 * q);
  __syncthreads();   // all fbr reads done before layer-0 zT writes recycle zbuf

#pragma unroll 1   // real loop: avoid cross-layer load hoisting -> spill (R6 lesson)
  for (int l = 0; l < NLAYER; ++l) {
    const ushort* Wl = g_wbf + l * NDIM * NDIM;

    // bias for this layer's 4 kout slabs (added post-MFMA; load latency hides under m1)
    float bv[4];
#pragma unroll
    for (int s = 0; s < 4; ++s) bv[s] = bias[l * NDIM + kbase + s * 16 + r];

    // ---- m1: z[16-node tile][64-kout region] = relu(h*W^T + b) ----
    f32x4 acc[4];
#pragma unroll
    for (int s = 0; s < 4; ++s) acc[s] = (f32x4){0.f, 0.f, 0.f, 0.f};
#pragma unroll
    for (int k0 = 0; k0 < NDIM; k0 += 32) {
      short8 ah = *(const short8*)(sh + (mt * 16 + r) * PH + k0 + 8 * q);
#pragma unroll
      for (int s = 0; s < 4; ++s) {
        short8 bw = *(const short8*)(Wl + (kbase + s * 16 + r) * NDIM + k0 + 8 * q);
        acc[s] = __builtin_amdgcn_mfma_f32_16x16x32_bf16(ah, bw, acc[s], 0, 0, 0);
      }
    }

    // ---- relu+bias -> zT[kout][node] in LDS (transposed: C-frag maps directly) ----
    // lane(r,q) of slab s holds z[node=mt*16+4q+jj][kout=kbase+s*16+r], jj=0..3
#pragma unroll
    for (int s = 0; s < 4; ++s) {
      uint2 u = {pkbf(fmaxf(acc[s][0] + bv[s], 0.f), fmaxf(acc[s][1] + bv[s], 0.f)),
                 pkbf(fmaxf(acc[s][2] + bv[s], 0.f), fmaxf(acc[s][3] + bv[s], 0.f))};
      *(uint2*)(zbuf + (kbase + s * 16 + r) * PZ + mt * 16 + 4 * q) = u;
    }
    __syncthreads();   // zT exchange

    // ---- m2: houtT[d in n0 slab][node'] = zT * (I+A)^T — A-frag is one b128 ----
    f32x4 acc2[4];
#pragma unroll
    for (int nt = 0; nt < 4; ++nt) acc2[nt] = (f32x4){0.f, 0.f, 0.f, 0.f};
#pragma unroll
    for (int kh = 0; kh < 2; ++kh) {
      // az lane(r,q): z[node=kh*32+8q+e][d=n0+r]  (8 consecutive nodes, contiguous)
      short8 az = *(const short8*)(zbuf + (n0 + r) * PZ + kh * 32 + 8 * q);
#pragma unroll
      for (int nt = 0; nt < 4; ++nt)
        acc2[nt] = __builtin_amdgcn_mfma_f32_16x16x32_bf16(az, fbr[kh][nt], acc2[nt], 0, 0, 0);
    }

    if (l < NLAYER - 1) {
      // h overwritten in place: all ah reads of this layer finished before the
      // zT barrier; next layer's reads separated by the barrier below.
#pragma unroll
      for (int nt = 0; nt < 4; ++nt) {
        f32x4 a = acc2[nt];
        uint2 u = {pkbf(a[0], a[1]), pkbf(a[2], a[3])};
        *(uint2*)(sh + (nt * 16 + r) * PH + n0 + 4 * q) = u;
      }
      __syncthreads();   // h exchange (also orders next layer's zT writes after az reads)
    } else {
      // ---- sum-pool: out[g][d] = sum_node' h[node'][d] ----
      f32x4 s;
#pragma unroll
      for (int i = 0; i < 4; ++i)
        s[i] = acc2[0][i] + acc2[1][i] + acc2[2][i] + acc2[3][i];
#pragma unroll
      for (int m = 1; m <= 8; m <<= 1) {
        s[0] += __shfl_xor(s[0], m);
        s[1] += __shfl_xor(s[1], m);
        s[2] += __shfl_xor(s[2], m);
        s[3] += __shfl_xor(s[3], m);
      }
      if (r == 0) {
        float4 o = {s[0], s[1], s[2], s[3]};
        *(float4*)(out + (size_t)g * NDIM + n0 + 4 * q) = o;
      }
    }
  }
}

extern "C" void kernel_launch(void* const* d_in, const int* in_sizes, int n_in,
                              void* d_out, int out_size, void* d_ws, size_t ws_size,
                              hipStream_t stream) {
  const int*   fps  = (const int*)d_in[0];
  const float* adj  = (const float*)d_in[1];
  const float* emb  = (const float*)d_in[2];
  const float* W    = (const float*)d_in[3];
  const float* bias = (const float*)d_in[4];
  float* out = (float*)d_out;

  hipLaunchKernelGGL(convert_w, dim3(192), dim3(256), 0, stream, W);
  hipLaunchKernelGGL(mpnn_mfma, dim3(NGRAPH), dim3(512), 0, stream,
                     fps, adj, emb, bias, out);
}

// Round 3
// 287.474 us; speedup vs baseline: 1.1403x; 1.1403x over previous
//
#include <hip/hip_runtime.h>

#define NGRAPH 4096
#define NNODE  64
#define NDIM   128
#define NLAYER 3
#define PH 136   // sh pitch (ushorts): 68 dwords === 4 mod 32 -> proven b128 row-read pattern
#define PZ 72    // zbuf pitch (ushorts): 36 dwords === 4 mod 32 (same family as R8's PA=72)

typedef __attribute__((ext_vector_type(8))) short short8;
typedef __attribute__((ext_vector_type(4))) float f32x4;
typedef __bf16 bf16x2 __attribute__((ext_vector_type(2)));

static __device__ inline ushort f2bf(float f) {  // RNE fp32 -> bf16 (fallback path)
  unsigned u = __float_as_uint(f);
  u += 0x7FFF + ((u >> 16) & 1);
  return (ushort)(u >> 16);
}

// packed fp32x2 -> bf16x2 in one HW instr on gfx950 (v_cvt_pk_bf16_f32)
static __device__ inline unsigned pkbf(float x, float y) {
#if __has_builtin(__builtin_amdgcn_cvt_pk_bf16_f32)
  bf16x2 v = __builtin_amdgcn_cvt_pk_bf16_f32(x, y);
  return __builtin_bit_cast(unsigned, v);
#else
  return (unsigned)f2bf(x) | ((unsigned)f2bf(y) << 16);
#endif
}

// W in bf16, native [l][k_out][d] layout (B-frag reads W rows directly).
__device__ __align__(16) ushort g_wbf[NLAYER * NDIM * NDIM];

__global__ __launch_bounds__(256) void convert_w(const float* __restrict__ W) {
  int i = blockIdx.x * 256 + threadIdx.x;   // 192 blocks, exact
  g_wbf[i] = f2bf(W[i]);
}

// R11 = R10 "split-z" dataflow with the register budget fixed.
// R10 post-mortem: __launch_bounds__(512,8) capped VGPR at 64, compiler chose
// 32 and spilled fbr+accumulators -> 210MB FETCH / 149MB WRITE of scratch
// traffic, 254us.  The dataflow itself was right (bank conflicts at all-time
// low).  (512,4) -> 128-VGPR cap; live set ~100 VGPRs fits, no spill, and
// 2 blocks/CU (16 waves) matches R8's proven-latency-hiding occupancy.
//  - m1: 1 node-tile x 4 kout-slabs per wave -> 32 ah b128 reads/block-layer.
//  - z written TRANSPOSED to LDS as packed C-frags -> m2 A-frag is one
//    contiguous ds_read_b128; zero bpermutes.
//  - (I+A) B-frags layer-invariant, hoisted to 32 VGPRs once per block.
//  - 2 barriers/layer; 35 KB LDS (zbuf recycled: adj stage -> zT).
__global__ __launch_bounds__(512, 4) void mpnn_mfma(
    const int* __restrict__ fps, const float* __restrict__ adj,
    const float* __restrict__ emb, const float* __restrict__ bias,
    float* __restrict__ out) {
  __shared__ __align__(16) ushort sh[NNODE * PH];    // h (in-place)      17408 B
  __shared__ __align__(16) ushort zbuf[NDIM * PZ];   // adj stage -> zT   18432 B

  const int g    = blockIdx.x;
  const int t    = threadIdx.x;
  const int w    = t >> 6;        // wave 0..7
  const int lane = t & 63;
  const int r    = lane & 15;     // MFMA row/col index
  const int q    = lane >> 4;     // quad 0..3
  const int mt    = w & 3;          // m1: this wave's 16-node tile
  const int kbase = (w >> 2) * 64;  // m1: this wave's 64-wide kout region (4 slabs)
  const int n0    = w << 4;         // m2: this wave's 16-wide d slab

  // ---- gather h0 = bf16(emb[fps]) into sh ----
  const int* fg = fps + g * NNODE;
#pragma unroll
  for (int it = 0; it < 4; ++it) {
    int idx = it * 512 + t;               // 2048 float4s
    int n = idx >> 5;
    int c = (idx & 31) << 2;
    float4 v = *(const float4*)(emb + fg[n] * NDIM + c);
    uint2 u = {pkbf(v.x, v.y), pkbf(v.z, v.w)};
    *(uint2*)(sh + n * PH + c) = u;
  }

  // ---- adjacency -> LDS: bf16(I + A), staged once, cooperatively coalesced ----
  const float* adjg = adj + (size_t)g * NNODE * NNODE;
#pragma unroll
  for (int it = 0; it < 2; ++it) {
    int idx = it * 512 + t;               // 1024 float4s
    int n = idx >> 4;
    int c = (idx & 15) << 2;
    float4 v = *(const float4*)(adjg + n * NNODE + c);
    v.x += (n == c + 0) ? 1.0f : 0.0f;    // fold residual: I + A
    v.y += (n == c + 1) ? 1.0f : 0.0f;
    v.z += (n == c + 2) ? 1.0f : 0.0f;
    v.w += (n == c + 3) ? 1.0f : 0.0f;
    uint2 u = {pkbf(v.x, v.y), pkbf(v.z, v.w)};
    *(uint2*)(zbuf + n * PZ + c) = u;
  }
  __syncthreads();

  // ---- (I+A) B-frags -> registers, once per block (layer-invariant) ----
  // fbr[kh][nt] lane(r,q): (I+A)[node'=nt*16+r][node=kh*32+8q+e]
  short8 fbr[2][4];
#pragma unroll
  for (int kh = 0; kh < 2; ++kh)
#pragma unroll
    for (int nt = 0; nt < 4; ++nt)
      fbr[kh][nt] = *(const short8*)(zbuf + (nt * 16 + r) * PZ + kh * 32 + 8 * q);
  __syncthreads();   // all fbr reads done before layer-0 zT writes recycle zbuf

#pragma unroll 1   // real loop: avoid cross-layer load hoisting -> spill (R6 lesson)
  for (int l = 0; l < NLAYER; ++l) {
    const ushort* Wl = g_wbf + l * NDIM * NDIM;

    // bias for this layer's 4 kout slabs (added post-MFMA; load latency hides under m1)
    float bv[4];
#pragma unroll
    for (int s = 0; s < 4; ++s) bv[s] = bias[l * NDIM + kbase + s * 16 + r];

    // ---- m1: z[16-node tile][64-kout region] = relu(h*W^T + b) ----
    f32x4 acc[4];
#pragma unroll
    for (int s = 0; s < 4; ++s) acc[s] = (f32x4){0.f, 0.f, 0.f, 0.f};
#pragma unroll
    for (int k0 = 0; k0 < NDIM; k0 += 32) {
      short8 ah = *(const short8*)(sh + (mt * 16 + r) * PH + k0 + 8 * q);
#pragma unroll
      for (int s = 0; s < 4; ++s) {
        short8 bw = *(const short8*)(Wl + (kbase + s * 16 + r) * NDIM + k0 + 8 * q);
        acc[s] = __builtin_amdgcn_mfma_f32_16x16x32_bf16(ah, bw, acc[s], 0, 0, 0);
      }
    }

    // ---- relu+bias -> zT[kout][node] in LDS (transposed: C-frag maps directly) ----
    // lane(r,q) of slab s holds z[node=mt*16+4q+jj][kout=kbase+s*16+r], jj=0..3
#pragma unroll
    for (int s = 0; s < 4; ++s) {
      uint2 u = {pkbf(fmaxf(acc[s][0] + bv[s], 0.f), fmaxf(acc[s][1] + bv[s], 0.f)),
                 pkbf(fmaxf(acc[s][2] + bv[s], 0.f), fmaxf(acc[s][3] + bv[s], 0.f))};
      *(uint2*)(zbuf + (kbase + s * 16 + r) * PZ + mt * 16 + 4 * q) = u;
    }
    __syncthreads();   // zT exchange

    // ---- m2: houtT[d in n0 slab][node'] = zT * (I+A)^T — A-frag is one b128 ----
    f32x4 acc2[4];
#pragma unroll
    for (int nt = 0; nt < 4; ++nt) acc2[nt] = (f32x4){0.f, 0.f, 0.f, 0.f};
#pragma unroll
    for (int kh = 0; kh < 2; ++kh) {
      // az lane(r,q): z[node=kh*32+8q+e][d=n0+r]  (8 consecutive nodes, contiguous)
      short8 az = *(const short8*)(zbuf + (n0 + r) * PZ + kh * 32 + 8 * q);
#pragma unroll
      for (int nt = 0; nt < 4; ++nt)
        acc2[nt] = __builtin_amdgcn_mfma_f32_16x16x32_bf16(az, fbr[kh][nt], acc2[nt], 0, 0, 0);
    }

    if (l < NLAYER - 1) {
      // h overwritten in place: all ah reads of this layer finished before the
      // zT barrier; next layer's reads separated by the barrier below.
#pragma unroll
      for (int nt = 0; nt < 4; ++nt) {
        f32x4 a = acc2[nt];
        uint2 u = {pkbf(a[0], a[1]), pkbf(a[2], a[3])};
        *(uint2*)(sh + (nt * 16 + r) * PH + n0 + 4 * q) = u;
      }
      __syncthreads();   // h exchange (also orders next layer's zT writes after az reads)
    } else {
      // ---- sum-pool: out[g][d] = sum_node' h[node'][d] ----
      f32x4 s;
#pragma unroll
      for (int i = 0; i < 4; ++i)
        s[i] = acc2[0][i] + acc2[1][i] + acc2[2][i] + acc2[3][i];
#pragma unroll
      for (int m = 1; m <= 8; m <<= 1) {
        s[0] += __shfl_xor(s[0], m);
        s[1] += __shfl_xor(s[1], m);
        s[2] += __shfl_xor(s[2], m);
        s[3] += __shfl_xor(s[3], m);
      }
      if (r == 0) {
        float4 o = {s[0], s[1], s[2], s[3]};
        *(float4*)(out + (size_t)g * NDIM + n0 + 4 * q) = o;
      }
    }
  }
}

extern "C" void kernel_launch(void* const* d_in, const int* in_sizes, int n_in,
                              void* d_out, int out_size, void* d_ws, size_t ws_size,
                              hipStream_t stream) {
  const int*   fps  = (const int*)d_in[0];
  const float* adj  = (const float*)d_in[1];
  const float* emb  = (const float*)d_in[2];
  const float* W    = (const float*)d_in[3];
  const float* bias = (const float*)d_in[4];
  float* out = (float*)d_out;

  hipLaunchKernelGGL(convert_w, dim3(192), dim3(256), 0, stream, W);
  hipLaunchKernelGGL(mpnn_mfma, dim3(NGRAPH), dim3(512), 0, stream,
                     fps, adj, emb, bias, out);
}

// Round 4
// 167.827 us; speedup vs baseline: 1.9532x; 1.7129x over previous
//
#include <hip/hip_runtime.h>

#define NGRAPH 4096
#define NNODE  64
#define NDIM   128
#define NLAYER 3
#define PH 136   // sh pitch (bf16): 68 dwords === 4 mod 32 -> bank-uniform b128 row reads

typedef __attribute__((ext_vector_type(8))) short short8;
typedef __attribute__((ext_vector_type(4))) float f32x4;
typedef __bf16 bf16x2 __attribute__((ext_vector_type(2)));

union S8 { short8 s8; unsigned d[4]; };

static __device__ inline ushort f2bf(float f) {  // RNE fp32 -> bf16 (fallback path)
  unsigned u = __float_as_uint(f);
  u += 0x7FFF + ((u >> 16) & 1);
  return (ushort)(u >> 16);
}

// packed fp32x2 -> bf16x2 in one HW instr on gfx950 (v_cvt_pk_bf16_f32)
static __device__ inline unsigned pkbf(float x, float y) {
#if __has_builtin(__builtin_amdgcn_cvt_pk_bf16_f32)
  bf16x2 v = __builtin_amdgcn_cvt_pk_bf16_f32(x, y);
  return __builtin_bit_cast(unsigned, v);
#else
  return (unsigned)f2bf(x) | ((unsigned)f2bf(y) << 16);
#endif
}

// W in bf16, native [l][k_out][d] layout (B-frag reads W rows directly).
__device__ __align__(16) ushort g_wbf[NLAYER * NDIM * NDIM];

__global__ __launch_bounds__(256) void convert_w(const float* __restrict__ W) {
  int i = blockIdx.x * 256 + threadIdx.x;   // 192 blocks, exact
  g_wbf[i] = f2bf(W[i]);
}

// R12 = R8 (best measured: 87.9us kernel) + ONE change: the (I+A) B-frags are
// layer-invariant, so the 64 fb ds_read_b128 per block-layer are replaced by a
// once-per-block register hoist fbr[2][4] (32 VGPRs), read from the
// cooperatively-staged LDS copy (R9's mistake was per-wave global loads here).
// adj is staged into sh1 (the pong buffer, dead until layer-0's m2 output), so
// sadj is deleted: LDS 44KB -> 34.8KB.  Barrier structure, bpermute transpose,
// W-load pattern all byte-identical to R8.  (512,4): 128-VGPR cap (R10 lesson:
// never let launch_bounds force a spill).
__global__ __launch_bounds__(512, 4) void mpnn_mfma(
    const int* __restrict__ fps, const float* __restrict__ adj,
    const float* __restrict__ emb, const float* __restrict__ bias,
    float* __restrict__ out) {
  __shared__ __align__(16) ushort sh0[NNODE * PH];    // h ping  17408 B
  __shared__ __align__(16) ushort sh1[NNODE * PH];    // adj stage -> h pong  17408 B

  const int g    = blockIdx.x;
  const int t    = threadIdx.x;
  const int w    = t >> 6;        // wave 0..7
  const int lane = t & 63;
  const int r    = lane & 15;     // MFMA row/col index
  const int q    = lane >> 4;     // quad 0..3
  const int n0   = w << 4;        // wave's 16-wide k_out slab (m1) == d slab (m2)

  // bpermute addresses for the z C-frag -> A-frag quad permute (R8-verified mapping)
  const int addr0 = (r + 32 * (q & 1)) << 2;   // p = 0,1
  const int addr1 = addr0 + 64;                // p = 2,3
  const bool hiQ  = (q >= 2);                  // source register select (node>=16 within 32)

  // ---- gather h0 = bf16(emb[fps]) into sh0 ----
  const int* fg = fps + g * NNODE;
#pragma unroll
  for (int it = 0; it < 4; ++it) {
    int idx = it * 512 + t;               // 2048 float4s
    int n = idx >> 5;
    int c = (idx & 31) << 2;
    float4 v = *(const float4*)(emb + fg[n] * NDIM + c);
    uint2 u = {pkbf(v.x, v.y), pkbf(v.z, v.w)};
    *(uint2*)(sh0 + n * PH + c) = u;
  }

  // ---- adjacency -> sh1: bf16(I + A), staged once, cooperatively coalesced ----
  const float* adjg = adj + (size_t)g * NNODE * NNODE;
#pragma unroll
  for (int it = 0; it < 2; ++it) {
    int idx = it * 512 + t;               // 1024 float4s
    int n = idx >> 4;
    int c = (idx & 15) << 2;
    float4 v = *(const float4*)(adjg + n * NNODE + c);
    v.x += (n == c + 0) ? 1.0f : 0.0f;    // fold residual: I + A
    v.y += (n == c + 1) ? 1.0f : 0.0f;
    v.z += (n == c + 2) ? 1.0f : 0.0f;
    v.w += (n == c + 3) ? 1.0f : 0.0f;
    uint2 u = {pkbf(v.x, v.y), pkbf(v.z, v.w)};
    *(uint2*)(sh1 + n * PH + c) = u;
  }

  // ---- bias for all layers -> registers ----
  float bv[NLAYER];
#pragma unroll
  for (int l = 0; l < NLAYER; ++l) bv[l] = bias[l * NDIM + n0 + r];

  __syncthreads();

  // ---- (I+A) B-frags -> registers, once per block (layer-invariant) ----
  // fbr[kh][nt] lane(r,q): (I+A)[node'=nt*16+r][node=kh*32+8q+e]  (R8 fb layout)
  short8 fbr[2][4];
#pragma unroll
  for (int kh = 0; kh < 2; ++kh)
#pragma unroll
    for (int nt = 0; nt < 4; ++nt)
      fbr[kh][nt] = *(const short8*)(sh1 + (nt * 16 + r) * PH + kh * 32 + 8 * q);
  __syncthreads();   // all fbr reads done before layer-0 m2 writes recycle sh1

#pragma unroll 1   // real loop: avoid cross-layer load hoisting -> spill (R6 lesson)
  for (int l = 0; l < NLAYER; ++l) {
    const ushort* shr = (l & 1) ? sh1 : sh0;   // read buffer
    ushort*       shw = (l & 1) ? sh0 : sh1;   // write buffer (ping-pong)
    const ushort* Wl  = g_wbf + l * NDIM * NDIM;

    // ---- m1: z[node][n0-slab(16)] = relu(h * W^T + b) ----
    f32x4 acc[4];
#pragma unroll
    for (int mt = 0; mt < 4; ++mt) acc[mt] = (f32x4){bv[l], bv[l], bv[l], bv[l]};
#pragma unroll
    for (int k0 = 0; k0 < NDIM; k0 += 32) {
      short8 bw = *(const short8*)(Wl + (n0 + r) * NDIM + k0 + 8 * q);
#pragma unroll
      for (int mt = 0; mt < 4; ++mt) {
        short8 ah = *(const short8*)(shr + (mt * 16 + r) * PH + k0 + 8 * q);
        acc[mt] = __builtin_amdgcn_mfma_f32_16x16x32_bf16(ah, bw, acc[mt], 0, 0, 0);
      }
    }
    // ---- relu -> packed bf16 in registers ----
    unsigned zc[4][2];   // [mt: node tile][node pair within quad-rows]
#pragma unroll
    for (int mt = 0; mt < 4; ++mt) {
      f32x4 a = acc[mt];
      zc[mt][0] = pkbf(fmaxf(a[0], 0.f), fmaxf(a[1], 0.f));
      zc[mt][1] = pkbf(fmaxf(a[2], 0.f), fmaxf(a[3], 0.f));
    }

    // ---- m2: houtT[d in n0-slab][node'] = zT * (I+A)^T, B-frags from registers ----
    f32x4 acc2[4];
#pragma unroll
    for (int nt = 0; nt < 4; ++nt) acc2[nt] = (f32x4){0.f, 0.f, 0.f, 0.f};
#pragma unroll
    for (int kh = 0; kh < 2; ++kh) {
      S8 az;
#pragma unroll
      for (int p = 0; p < 4; ++p) {
        int comp = p & 1;
        int lo = __builtin_amdgcn_ds_bpermute((p < 2) ? addr0 : addr1,
                                              (int)zc[2 * kh][comp]);
        int hi = __builtin_amdgcn_ds_bpermute((p < 2) ? addr0 : addr1,
                                              (int)zc[2 * kh + 1][comp]);
        az.d[p] = (unsigned)(hiQ ? hi : lo);
      }
#pragma unroll
      for (int nt = 0; nt < 4; ++nt)
        acc2[nt] = __builtin_amdgcn_mfma_f32_16x16x32_bf16(az.s8, fbr[kh][nt], acc2[nt], 0, 0, 0);
    }

    if (l < NLAYER - 1) {
      // write h into the OTHER buffer: no pre-barrier needed
#pragma unroll
      for (int nt = 0; nt < 4; ++nt) {
        f32x4 a = acc2[nt];
        uint2 u = {pkbf(a[0], a[1]), pkbf(a[2], a[3])};
        *(uint2*)(shw + (nt * 16 + r) * PH + n0 + 4 * q) = u;
      }
      __syncthreads();   // single barrier per layer
    } else {
      // ---- sum-pool: out[g][d] = sum_node' h[node'][d] ----
      f32x4 s;
#pragma unroll
      for (int i = 0; i < 4; ++i)
        s[i] = acc2[0][i] + acc2[1][i] + acc2[2][i] + acc2[3][i];
#pragma unroll
      for (int m = 1; m <= 8; m <<= 1) {
        s[0] += __shfl_xor(s[0], m);
        s[1] += __shfl_xor(s[1], m);
        s[2] += __shfl_xor(s[2], m);
        s[3] += __shfl_xor(s[3], m);
      }
      if (r == 0) {
        float4 o = {s[0], s[1], s[2], s[3]};
        *(float4*)(out + (size_t)g * NDIM + n0 + 4 * q) = o;
      }
    }
  }
}

extern "C" void kernel_launch(void* const* d_in, const int* in_sizes, int n_in,
                              void* d_out, int out_size, void* d_ws, size_t ws_size,
                              hipStream_t stream) {
  const int*   fps  = (const int*)d_in[0];
  const float* adj  = (const float*)d_in[1];
  const float* emb  = (const float*)d_in[2];
  const float* W    = (const float*)d_in[3];
  const float* bias = (const float*)d_in[4];
  float* out = (float*)d_out;

  hipLaunchKernelGGL(convert_w, dim3(192), dim3(256), 0, stream, W);
  hipLaunchKernelGGL(mpnn_mfma, dim3(NGRAPH), dim3(512), 0, stream,
                     fps, adj, emb, bias, out);
}

// Round 5
// 157.336 us; speedup vs baseline: 2.0834x; 1.0667x over previous
//
#include <hip/hip_runtime.h>

#define NGRAPH 4096
#define NNODE  64
#define NDIM   128
#define NLAYER 3
#define PH 136   // sh pitch (bf16): 68 dwords === 4 mod 32 -> bank-uniform b128 row reads

typedef __attribute__((ext_vector_type(8))) short short8;
typedef __attribute__((ext_vector_type(4))) float f32x4;
typedef __bf16 bf16x2 __attribute__((ext_vector_type(2)));

union S8 { short8 s8; unsigned d[4]; };

static __device__ inline ushort f2bf(float f) {  // RNE fp32 -> bf16 (fallback path)
  unsigned u = __float_as_uint(f);
  u += 0x7FFF + ((u >> 16) & 1);
  return (ushort)(u >> 16);
}

// packed fp32x2 -> bf16x2 in one HW instr on gfx950 (v_cvt_pk_bf16_f32)
static __device__ inline unsigned pkbf(float x, float y) {
#if __has_builtin(__builtin_amdgcn_cvt_pk_bf16_f32)
  bf16x2 v = __builtin_amdgcn_cvt_pk_bf16_f32(x, y);
  return __builtin_bit_cast(unsigned, v);
#else
  return (unsigned)f2bf(x) | ((unsigned)f2bf(y) << 16);
#endif
}

// W in bf16, native [l][k_out][d] layout (B-frag reads W rows directly).
__device__ __align__(16) ushort g_wbf[NLAYER * NDIM * NDIM];

__global__ __launch_bounds__(256) void convert_w(const float* __restrict__ W) {
  int i = blockIdx.x * 256 + threadIdx.x;   // 192 blocks, exact
  g_wbf[i] = f2bf(W[i]);
}

// R13 = R9's wave shape x R12's staging/hoist/ping-pong.
//  - 4-wave (256-thread) blocks, one graph each: wave w owns a 32-wide kout
//    region (two 16-slabs).  ah[mt] loaded ONCE per k-step feeds both slabs:
//    64 ah b128 reads/graph-layer (vs 128 in R8/R12).  W rows read by exactly
//    one wave (R11's 4x redundancy avoided).
//  - adj cooperatively staged (coalesced) into sh1/pong, then (I+A) B-frags
//    hoisted to fbr[2][4] registers once per block (layer-invariant) -- R12's
//    proven fix for R9's per-wave redundant global loads.
//  - m2 z-transpose fully in-register via the R8-verified bpermute mapping,
//    per 16-slab; ping-pong h buffers -> single barrier per layer.
//  - LDS 34.8 KB -> 4 blocks/CU; (256,4): 128-VGPR cap (R9 compiled this
//    register set to 64 VGPR cleanly; R10 lesson: never force a spill).
__global__ __launch_bounds__(256, 4) void mpnn_mfma(
    const int* __restrict__ fps, const float* __restrict__ adj,
    const float* __restrict__ emb, const float* __restrict__ bias,
    float* __restrict__ out) {
  __shared__ __align__(16) ushort sh0[NNODE * PH];    // h ping  17408 B
  __shared__ __align__(16) ushort sh1[NNODE * PH];    // adj stage -> h pong  17408 B

  const int g    = blockIdx.x;
  const int t    = threadIdx.x;
  const int w    = t >> 6;        // wave 0..3
  const int lane = t & 63;
  const int r    = lane & 15;     // MFMA row/col index
  const int q    = lane >> 4;     // quad 0..3
  const int n0   = w << 5;        // wave's 32-wide kout region (m1) == d region (m2)

  // bpermute addresses for the z C-frag -> A-frag quad permute (R8-verified mapping)
  const int addr0 = (r + 32 * (q & 1)) << 2;   // p = 0,1
  const int addr1 = addr0 + 64;                // p = 2,3
  const bool hiQ  = (q >= 2);                  // source register select (node>=16 within 32)

  // ---- gather h0 = bf16(emb[fps]) into sh0 ----
  const int* fg = fps + g * NNODE;
#pragma unroll
  for (int it = 0; it < 8; ++it) {
    int idx = it * 256 + t;               // 2048 float4s
    int n = idx >> 5;
    int c = (idx & 31) << 2;
    float4 v = *(const float4*)(emb + fg[n] * NDIM + c);
    uint2 u = {pkbf(v.x, v.y), pkbf(v.z, v.w)};
    *(uint2*)(sh0 + n * PH + c) = u;
  }

  // ---- adjacency -> sh1: bf16(I + A), staged once, cooperatively coalesced ----
  const float* adjg = adj + (size_t)g * NNODE * NNODE;
#pragma unroll
  for (int it = 0; it < 4; ++it) {
    int idx = it * 256 + t;               // 1024 float4s
    int n = idx >> 4;
    int c = (idx & 15) << 2;
    float4 v = *(const float4*)(adjg + n * NNODE + c);
    v.x += (n == c + 0) ? 1.0f : 0.0f;    // fold residual: I + A
    v.y += (n == c + 1) ? 1.0f : 0.0f;
    v.z += (n == c + 2) ? 1.0f : 0.0f;
    v.w += (n == c + 3) ? 1.0f : 0.0f;
    uint2 u = {pkbf(v.x, v.y), pkbf(v.z, v.w)};
    *(uint2*)(sh1 + n * PH + c) = u;
  }

  // ---- bias for all layers, both slabs -> registers ----
  float bv[NLAYER][2];
#pragma unroll
  for (int l = 0; l < NLAYER; ++l) {
    bv[l][0] = bias[l * NDIM + n0 + r];
    bv[l][1] = bias[l * NDIM + n0 + 16 + r];
  }

  __syncthreads();

  // ---- (I+A) B-frags -> registers, once per block (layer-invariant) ----
  // fbr[kh][nt] lane(r,q): (I+A)[node'=nt*16+r][node=kh*32+8q+e]
  short8 fbr[2][4];
#pragma unroll
  for (int kh = 0; kh < 2; ++kh)
#pragma unroll
    for (int nt = 0; nt < 4; ++nt)
      fbr[kh][nt] = *(const short8*)(sh1 + (nt * 16 + r) * PH + kh * 32 + 8 * q);
  __syncthreads();   // all fbr reads done before layer-0 m2 writes recycle sh1

#pragma unroll 1   // real loop: avoid cross-layer load hoisting -> spill (R6 lesson)
  for (int l = 0; l < NLAYER; ++l) {
    const ushort* shr = (l & 1) ? sh1 : sh0;   // read buffer
    ushort*       shw = (l & 1) ? sh0 : sh1;   // write buffer (ping-pong)
    const ushort* Wl  = g_wbf + l * NDIM * NDIM;

    // ---- m1: z[node][n0-region(32)] = relu(h * W^T + b), two 16-slabs ----
    f32x4 acc[2][4];
#pragma unroll
    for (int s = 0; s < 2; ++s)
#pragma unroll
      for (int mt = 0; mt < 4; ++mt)
        acc[s][mt] = (f32x4){bv[l][s], bv[l][s], bv[l][s], bv[l][s]};
#pragma unroll
    for (int k0 = 0; k0 < NDIM; k0 += 32) {
      short8 ah[4];                       // loaded ONCE, feeds both slabs
#pragma unroll
      for (int mt = 0; mt < 4; ++mt)
        ah[mt] = *(const short8*)(shr + (mt * 16 + r) * PH + k0 + 8 * q);
#pragma unroll
      for (int s = 0; s < 2; ++s) {
        short8 bw = *(const short8*)(Wl + (n0 + s * 16 + r) * NDIM + k0 + 8 * q);
#pragma unroll
        for (int mt = 0; mt < 4; ++mt)
          acc[s][mt] = __builtin_amdgcn_mfma_f32_16x16x32_bf16(ah[mt], bw, acc[s][mt], 0, 0, 0);
      }
    }

    // ---- relu -> packed bf16 in registers ----
    unsigned zc[2][4][2];   // [slab][mt: node tile][node pair within quad-rows]
#pragma unroll
    for (int s = 0; s < 2; ++s)
#pragma unroll
      for (int mt = 0; mt < 4; ++mt) {
        f32x4 a = acc[s][mt];
        zc[s][mt][0] = pkbf(fmaxf(a[0], 0.f), fmaxf(a[1], 0.f));
        zc[s][mt][1] = pkbf(fmaxf(a[2], 0.f), fmaxf(a[3], 0.f));
      }

    // ---- m2: houtT[d in n0-region][node'] = zT * (I+A)^T, B-frags from registers ----
    f32x4 acc2[2][4];
#pragma unroll
    for (int s = 0; s < 2; ++s)
#pragma unroll
      for (int nt = 0; nt < 4; ++nt) acc2[s][nt] = (f32x4){0.f, 0.f, 0.f, 0.f};
#pragma unroll
    for (int s = 0; s < 2; ++s) {
#pragma unroll
      for (int kh = 0; kh < 2; ++kh) {
        S8 az;
#pragma unroll
        for (int p = 0; p < 4; ++p) {
          int comp = p & 1;
          int lo = __builtin_amdgcn_ds_bpermute((p < 2) ? addr0 : addr1,
                                                (int)zc[s][2 * kh][comp]);
          int hi = __builtin_amdgcn_ds_bpermute((p < 2) ? addr0 : addr1,
                                                (int)zc[s][2 * kh + 1][comp]);
          az.d[p] = (unsigned)(hiQ ? hi : lo);
        }
#pragma unroll
        for (int nt = 0; nt < 4; ++nt)
          acc2[s][nt] = __builtin_amdgcn_mfma_f32_16x16x32_bf16(az.s8, fbr[kh][nt], acc2[s][nt], 0, 0, 0);
      }
    }

    if (l < NLAYER - 1) {
      // write h into the OTHER buffer: no pre-barrier needed
#pragma unroll
      for (int s = 0; s < 2; ++s)
#pragma unroll
        for (int nt = 0; nt < 4; ++nt) {
          f32x4 a = acc2[s][nt];
          uint2 u = {pkbf(a[0], a[1]), pkbf(a[2], a[3])};
          *(uint2*)(shw + (nt * 16 + r) * PH + n0 + s * 16 + 4 * q) = u;
        }
      __syncthreads();   // single barrier per layer
    } else {
      // ---- sum-pool: out[g][d] = sum_node' h[node'][d] ----
#pragma unroll
      for (int s = 0; s < 2; ++s) {
        f32x4 sum;
#pragma unroll
        for (int i = 0; i < 4; ++i)
          sum[i] = acc2[s][0][i] + acc2[s][1][i] + acc2[s][2][i] + acc2[s][3][i];
#pragma unroll
        for (int m = 1; m <= 8; m <<= 1) {
          sum[0] += __shfl_xor(sum[0], m);
          sum[1] += __shfl_xor(sum[1], m);
          sum[2] += __shfl_xor(sum[2], m);
          sum[3] += __shfl_xor(sum[3], m);
        }
        if (r == 0) {
          float4 o = {sum[0], sum[1], sum[2], sum[3]};
          *(float4*)(out + (size_t)g * NDIM + n0 + s * 16 + 4 * q) = o;
        }
      }
    }
  }
}

extern "C" void kernel_launch(void* const* d_in, const int* in_sizes, int n_in,
                              void* d_out, int out_size, void* d_ws, size_t ws_size,
                              hipStream_t stream) {
  const int*   fps  = (const int*)d_in[0];
  const float* adj  = (const float*)d_in[1];
  const float* emb  = (const float*)d_in[2];
  const float* W    = (const float*)d_in[3];
  const float* bias = (const float*)d_in[4];
  float* out = (float*)d_out;

  hipLaunchKernelGGL(convert_w, dim3(192), dim3(256), 0, stream, W);
  hipLaunchKernelGGL(mpnn_mfma, dim3(NGRAPH), dim3(256), 0, stream,
                     fps, adj, emb, bias, out);
}